// Round 5
// baseline (995.058 us; speedup 1.0000x reference)
//
#include <hip/hip_runtime.h>
#include <hip/hip_cooperative_groups.h>
#include <type_traits>
namespace cg = cooperative_groups;

#define N_NODES 50000
#define N_EDGES 400000
#define DIM     128
#define HID     60
#define NCLS    40
#define F3      180
#define PADW    192
#define LDSW    200
#define SLOTS   64
#define MTILES  3125   // 50000/16
#define WSLOT   (64*192)
#define GB      782    // ceil(MTILES/4)
#define PBLK    1563   // ceil(50000/32)

typedef __bf16 bf16x8 __attribute__((ext_vector_type(8)));
typedef unsigned short u16x8 __attribute__((ext_vector_type(8)));
typedef float  f32x4  __attribute__((ext_vector_type(4)));
typedef unsigned short u16;
typedef unsigned int   u32;

__device__ __forceinline__ u16 f2bf(float f){
  u32 x = __float_as_uint(f);
  x += 0x7fffu + ((x>>16)&1u);   // RNE
  return (u16)(x>>16);
}
__device__ __forceinline__ float blo(u32 v){ return __uint_as_float(v<<16); }
__device__ __forceinline__ float bhi(u32 v){ return __uint_as_float(v & 0xffff0000u); }
__device__ __forceinline__ u32 pk(float a, float b){ return (u32)f2bf(a) | ((u32)f2bf(b)<<16); }

__device__ __forceinline__ void acc8(float* a, uint4 V, float wt){
  a[0] = fmaf(wt, blo(V.x), a[0]); a[1] = fmaf(wt, bhi(V.x), a[1]);
  a[2] = fmaf(wt, blo(V.y), a[2]); a[3] = fmaf(wt, bhi(V.y), a[3]);
  a[4] = fmaf(wt, blo(V.z), a[4]); a[5] = fmaf(wt, bhi(V.z), a[5]);
  a[6] = fmaf(wt, blo(V.w), a[6]); a[7] = fmaf(wt, bhi(V.w), a[7]);
}

struct MegaArgs {
  const float *x; const int *ei;
  const float *w1,*w2,*w3,*wl;
  const float *cb0,*cb1,*cb2;
  const float *g0,*b0,*m0,*v0;
  const float *g1,*b1,*m1,*v1;
  const float *g2,*b2,*m2,*v2;
  const float *linb;
  float *outp;
  int *cnt; u16 *slots; float *dis;
  float *S; float *T; u16 *wpad;
  u16 *CA,*CB,*Y1,*Y2,*Z;
};

// ---------- A-fragment loaders ----------
__device__ __forceinline__ bf16x8 lda8(const u16* p){ return *(const bf16x8*)p; }
__device__ __forceinline__ bf16x8 lda8(const float* p){
  f32x4 v0 = ((const f32x4*)p)[0];
  f32x4 v1 = ((const f32x4*)p)[1];
  u16x8 t;
  #pragma unroll
  for (int j = 0; j < 4; ++j){ t[j] = f2bf(v0[j]); t[j+4] = f2bf(v1[j]); }
  return __builtin_bit_cast(bf16x8, t);
}

// ---------- fused 3-power GEMM phase (bit-identical to r0 k_gemm3) ----------
template<typename TA, int KS>
__device__ void gemm3_phase(const TA* __restrict__ A, int lda,
        const u16* __restrict__ Wbase, u16* __restrict__ C0,
        u16* __restrict__ Y1, u16* __restrict__ Y2,
        const float* __restrict__ S, const float* __restrict__ T,
        u16* Wl, int vb0, int vstr, int tid){
  for (int vb = vb0; vb < GB; vb += vstr){
    int mt = vb*4 + (tid >> 6);
    bool active = mt < MTILES;
    int lane = tid & 63, rr = lane & 15, kg = lane >> 4;
    int mrow = active ? mt*16 + rr : 0;
    const TA* Ap = A + (size_t)mrow*lda + kg*8;
    bf16x8 a[KS];
    #pragma unroll
    for (int ks = 0; ks < KS; ++ks) a[ks] = lda8(Ap + ks*32);
    #pragma unroll
    for (int p = 0; p < 3; ++p){
      const u16* Wp = Wbase + p*WSLOT;
      for (int t2 = tid; t2 < 1536; t2 += 256){
        int r = t2 / 24, c8 = t2 % 24;
        *(u16x8*)(&Wl[r*LDSW + c8*8]) = *(const u16x8*)(Wp + r*192 + c8*8);
      }
      __syncthreads();
      f32x4 acc[4] = {{0,0,0,0},{0,0,0,0},{0,0,0,0},{0,0,0,0}};
      #pragma unroll
      for (int ks = 0; ks < KS; ++ks){
        int kb = ks*32 + kg*8;
        #pragma unroll
        for (int ct = 0; ct < 4; ++ct){
          bf16x8 b = *(const bf16x8*)(&Wl[(ct*16 + rr)*LDSW + kb]);
          acc[ct] = __builtin_amdgcn_mfma_f32_16x16x32_bf16(a[ks], b, acc[ct], 0, 0, 0);
        }
      }
      if (active){
        int orow = mt*16 + kg*4;
        u16* out = (p==0) ? C0 : (p==1) ? Y1 : Y2;
        int  ldo = (p==0) ? PADW : 64;
        #pragma unroll
        for (int ct = 0; ct < 4; ++ct){
          int col = ct*16 + rr;
          if (col < HID){
            float sS = (p==0) ? S[col] : 1.f;
            float tT = (p==0) ? T[col] : 0.f;
            #pragma unroll
            for (int r2 = 0; r2 < 4; ++r2)
              out[(size_t)(orow + r2)*ldo + col] = f2bf(acc[ct][r2]*sS + tT);
          }
        }
      }
      __syncthreads();
    }
  }
}

// ---------- dual-stream hop phase (bit-identical to r0 k_prop2) ----------
__device__ void prop2_phase(const u16* __restrict__ inA, u16* __restrict__ outA,
        const float* __restrict__ SA, const float* __restrict__ TA,
        const u16* __restrict__ inB, u16* __restrict__ outB,
        const float* __restrict__ dis, const int* __restrict__ n4a,
        const u16* __restrict__ slots, int bid, int nbk, int tid){
  int lane = tid & 63, g = lane >> 3, c = lane & 7;
  for (int v = bid; v < PBLK; v += nbk){
    int node = v*32 + (tid >> 6)*8 + g;
    if (node >= N_NODES) continue;
    float di = dis[node];
    int n4 = n4a[node];
    const u16* nb = slots + node*SLOTS;
    float aA[8] = {0,0,0,0,0,0,0,0}, aB[8] = {0,0,0,0,0,0,0,0};
    for (int e = 0; e < n4; e += 4){
      uint2 s4 = *(const uint2*)(nb + e);
      int r0 = s4.x & 0xffff, r1 = s4.x >> 16;
      int r2 = s4.y & 0xffff, r3 = s4.y >> 16;
      float w0 = dis[r0], w1 = dis[r1], w2 = dis[r2], w3 = dis[r3];
      uint4 A0 = ((const uint4*)(inA + (size_t)r0*64))[c];
      uint4 A1 = ((const uint4*)(inA + (size_t)r1*64))[c];
      uint4 A2 = ((const uint4*)(inA + (size_t)r2*64))[c];
      uint4 A3 = ((const uint4*)(inA + (size_t)r3*64))[c];
      uint4 B0 = ((const uint4*)(inB + (size_t)r0*64))[c];
      uint4 B1 = ((const uint4*)(inB + (size_t)r1*64))[c];
      uint4 B2 = ((const uint4*)(inB + (size_t)r2*64))[c];
      uint4 B3 = ((const uint4*)(inB + (size_t)r3*64))[c];
      acc8(aA, A0, w0); acc8(aA, A1, w1); acc8(aA, A2, w2); acc8(aA, A3, w3);
      acc8(aB, B0, w0); acc8(aB, B1, w1); acc8(aB, B2, w2); acc8(aB, B3, w3);
    }
    int cc = c*8;
    float y0 = di*aA[0]*SA[cc]   + TA[cc],   y1 = di*aA[1]*SA[cc+1] + TA[cc+1];
    float y2 = di*aA[2]*SA[cc+2] + TA[cc+2], y3 = di*aA[3]*SA[cc+3] + TA[cc+3];
    float y4 = di*aA[4]*SA[cc+4] + TA[cc+4], y5 = di*aA[5]*SA[cc+5] + TA[cc+5];
    float y6 = di*aA[6]*SA[cc+6] + TA[cc+6], y7 = di*aA[7]*SA[cc+7] + TA[cc+7];
    u16* oa = outA + (size_t)node*PADW + cc;
    uint2 w01 = {pk(y0,y1), pk(y2,y3)}, w23 = {pk(y4,y5), pk(y6,y7)};
    *(uint2*)(oa)     = w01;
    *(uint2*)(oa + 4) = w23;
    uint4 ob = {pk(di*aB[0],di*aB[1]), pk(di*aB[2],di*aB[3]),
                pk(di*aB[4],di*aB[5]), pk(di*aB[6],di*aB[7])};
    ((uint4*)(outB + (size_t)node*64))[c] = ob;
  }
}

// ---------- single-stream hop phase (bit-identical to r0 k_prop1) ----------
__device__ void prop1_phase(const u16* __restrict__ inA, u16* __restrict__ outA,
        const float* __restrict__ SA, const float* __restrict__ TA,
        const float* __restrict__ dis, const int* __restrict__ n4a,
        const u16* __restrict__ slots, int bid, int nbk, int tid){
  int lane = tid & 63, g = lane >> 3, c = lane & 7;
  for (int v = bid; v < PBLK; v += nbk){
    int node = v*32 + (tid >> 6)*8 + g;
    if (node >= N_NODES) continue;
    float di = dis[node];
    int n4 = n4a[node];
    const u16* nb = slots + node*SLOTS;
    float a[8] = {0,0,0,0,0,0,0,0};
    for (int e = 0; e < n4; e += 4){
      uint2 s4 = *(const uint2*)(nb + e);
      int r0 = s4.x & 0xffff, r1 = s4.x >> 16;
      int r2 = s4.y & 0xffff, r3 = s4.y >> 16;
      float w0 = dis[r0], w1 = dis[r1], w2 = dis[r2], w3 = dis[r3];
      uint4 v0 = ((const uint4*)(inA + (size_t)r0*64))[c];
      uint4 v1 = ((const uint4*)(inA + (size_t)r1*64))[c];
      uint4 v2 = ((const uint4*)(inA + (size_t)r2*64))[c];
      uint4 v3 = ((const uint4*)(inA + (size_t)r3*64))[c];
      acc8(a, v0, w0); acc8(a, v1, w1); acc8(a, v2, w2); acc8(a, v3, w3);
    }
    int cc = c*8;
    float y0 = di*a[0]*SA[cc]   + TA[cc],   y1 = di*a[1]*SA[cc+1] + TA[cc+1];
    float y2 = di*a[2]*SA[cc+2] + TA[cc+2], y3 = di*a[3]*SA[cc+3] + TA[cc+3];
    float y4 = di*a[4]*SA[cc+4] + TA[cc+4], y5 = di*a[5]*SA[cc+5] + TA[cc+5];
    float y6 = di*a[6]*SA[cc+6] + TA[cc+6], y7 = di*a[7]*SA[cc+7] + TA[cc+7];
    u16* oa = outA + (size_t)node*PADW + cc;
    uint2 w01 = {pk(y0,y1), pk(y2,y3)}, w23 = {pk(y4,y5), pk(y6,y7)};
    *(uint2*)(oa)     = w01;
    *(uint2*)(oa + 4) = w23;
  }
}

// ---------- final linear phase (bit-identical to r0 k_gemmf) ----------
__device__ void gemmf_phase(const u16* __restrict__ A, const u16* __restrict__ Wp,
        float* __restrict__ out, const float* __restrict__ T,
        u16* Wl, int bid, int nbk, int tid){
  for (int t2 = tid; t2 < 1536; t2 += 256){
    int r = t2 / 24, c8 = t2 % 24;
    *(u16x8*)(&Wl[r*LDSW + c8*8]) = *(const u16x8*)(Wp + r*192 + c8*8);
  }
  __syncthreads();
  int lane = tid & 63, rr = lane & 15, kg = lane >> 4;
  for (int vb = bid; vb < GB; vb += nbk){
    int mt = vb*4 + (tid >> 6);
    if (mt >= MTILES) continue;
    const u16* Ap = A + (size_t)(mt*16 + rr)*PADW + kg*8;
    f32x4 acc[4] = {{0,0,0,0},{0,0,0,0},{0,0,0,0},{0,0,0,0}};
    for (int ks = 0; ks < 6; ++ks){
      bf16x8 a = *(const bf16x8*)(Ap + ks*32);
      int kb = ks*32 + kg*8;
      #pragma unroll
      for (int ct = 0; ct < 4; ++ct){
        bf16x8 b = *(const bf16x8*)(&Wl[(ct*16 + rr)*LDSW + kb]);
        acc[ct] = __builtin_amdgcn_mfma_f32_16x16x32_bf16(a, b, acc[ct], 0, 0, 0);
      }
    }
    int orow = mt*16 + kg*4;
    #pragma unroll
    for (int ct = 0; ct < 4; ++ct){
      int col = ct*16 + rr;
      if (col < NCLS){
        float tT = T[col];
        #pragma unroll
        for (int r2 = 0; r2 < 4; ++r2)
          out[(size_t)(orow + r2)*NCLS + col] = acc[ct][r2] + tT;
      }
    }
  }
}

// =================== the mega-kernel: 14 dispatches -> 1 ===================
__global__ __launch_bounds__(256, 4) void k_mega(MegaArgs A){
  cg::grid_group gg = cg::this_grid();
  __shared__ u16 Wl[64*LDSW];
  const int tid = threadIdx.x;
  const int nb  = gridDim.x;
  const int gt  = blockIdx.x*256 + tid;
  const int NT  = nb*256;

  // ---- P0: zero cnt | dis sentinel | S,T prep | weight pad (all independent) ----
  for (int i = gt; i < N_NODES; i += NT) A.cnt[i] = 0;
  if (gt == 0) A.dis[N_NODES] = 0.f;
  for (int i = gt; i < 4*PADW; i += NT){
    int lb = i / PADW, c = i - lb*PADW;
    float s = 0.f, t = 0.f;
    if (lb < 3){
      const float* g  = lb==0?A.g0 :lb==1?A.g1 :A.g2;
      const float* bb = lb==0?A.b0 :lb==1?A.b1 :A.b2;
      const float* m  = lb==0?A.m0 :lb==1?A.m1 :A.m2;
      const float* v  = lb==0?A.v0 :lb==1?A.v1 :A.v2;
      const float* cb = lb==0?A.cb0:lb==1?A.cb1:A.cb2;
      if (c < F3){
        float sv = g[c] * rsqrtf(v[c] + 1e-5f);
        s = sv;
        t = cb[c]*sv + bb[c] - m[c]*sv;    // conv bias folded into BN
      }
    } else if (c < NCLS){ s = 1.f; t = A.linb[c]; }
    A.S[i] = s; A.T[i] = t;
  }
  for (int i = gt; i < 10*WSLOT; i += NT){
    int sl = i / WSLOT, idx = i - sl*WSLOT;
    int r = idx / 192, k = idx - r*192;
    const float* src; int rows, K;
    if (sl < 3)      { src = A.w1 + sl*HID*DIM;      rows = HID;  K = DIM; }
    else if (sl < 6) { src = A.w2 + (sl-3)*HID*F3;   rows = HID;  K = F3;  }
    else if (sl < 9) { src = A.w3 + (sl-6)*HID*F3;   rows = HID;  K = F3;  }
    else             { src = A.wl;                   rows = NCLS; K = F3;  }
    u16 vv = 0;
    if (r < rows && k < K) vv = f2bf(src[r*K + k]);
    A.wpad[i] = vv;
  }
  gg.sync();

  // ---- P1: GEMM layer-1 (blocks < GB) CONCURRENT with edge scatter (rest) ----
  if (nb >= GB + 16){
    if (blockIdx.x < GB){
      gemm3_phase<float,4>(A.x, DIM, A.wpad, A.CA, A.Y1, A.Y2, A.S, A.T, Wl,
                           blockIdx.x, GB, tid);
    } else {
      for (int e = (blockIdx.x - GB)*256 + tid; e < N_EDGES; e += (nb - GB)*256){
        int c = A.ei[N_EDGES + e];
        int pos = atomicAdd(&A.cnt[c], 1);
        if (pos < SLOTS) A.slots[c*SLOTS + pos] = (u16)A.ei[e];
      }
    }
  } else {                    // fallback for small co-resident grids
    gemm3_phase<float,4>(A.x, DIM, A.wpad, A.CA, A.Y1, A.Y2, A.S, A.T, Wl,
                         blockIdx.x, nb, tid);
    for (int e = gt; e < N_EDGES; e += NT){
      int c = A.ei[N_EDGES + e];
      int pos = atomicAdd(&A.cnt[c], 1);
      if (pos < SLOTS) A.slots[c*SLOTS + pos] = (u16)A.ei[e];
    }
  }
  gg.sync();

  // ---- P2: dis + self-loop + pad (needs final cnt) ----
  for (int gid = gt; gid < N_NODES; gid += NT){
    int d = min(A.cnt[gid], SLOTS - 5);
    A.dis[gid] = rsqrtf((float)(d + 1));
    int d4 = (d + 4) & ~3;
    u16* s = A.slots + gid*SLOTS;
    s[d] = (u16)gid;
    for (int p = d + 1; p < d4; ++p) s[p] = (u16)N_NODES;
    A.cnt[gid] = d4;
  }
  gg.sync();

  // ---- layer 1 hops ----
  prop2_phase(A.Y1, A.CA + 60, A.S + 60, A.T + 60, A.Y2, A.Z,
              A.dis, A.cnt, A.slots, blockIdx.x, nb, tid);
  gg.sync();
  prop1_phase(A.Z, A.CA + 120, A.S + 120, A.T + 120,
              A.dis, A.cnt, A.slots, blockIdx.x, nb, tid);
  gg.sync();

  // ---- layer 2 ----
  gemm3_phase<u16,6>(A.CA, PADW, A.wpad + 3*WSLOT, A.CB, A.Y1, A.Y2,
                     A.S + PADW, A.T + PADW, Wl, blockIdx.x, nb, tid);
  gg.sync();
  prop2_phase(A.Y1, A.CB + 60, A.S + PADW + 60, A.T + PADW + 60, A.Y2, A.Z,
              A.dis, A.cnt, A.slots, blockIdx.x, nb, tid);
  gg.sync();
  prop1_phase(A.Z, A.CB + 120, A.S + PADW + 120, A.T + PADW + 120,
              A.dis, A.cnt, A.slots, blockIdx.x, nb, tid);
  gg.sync();

  // ---- layer 3 ----
  gemm3_phase<u16,6>(A.CB, PADW, A.wpad + 6*WSLOT, A.CA, A.Y1, A.Y2,
                     A.S + 2*PADW, A.T + 2*PADW, Wl, blockIdx.x, nb, tid);
  gg.sync();
  prop2_phase(A.Y1, A.CA + 60, A.S + 2*PADW + 60, A.T + 2*PADW + 60, A.Y2, A.Z,
              A.dis, A.cnt, A.slots, blockIdx.x, nb, tid);
  gg.sync();
  prop1_phase(A.Z, A.CA + 120, A.S + 2*PADW + 120, A.T + 2*PADW + 120,
              A.dis, A.cnt, A.slots, blockIdx.x, nb, tid);
  gg.sync();

  // ---- final linear ----
  gemmf_phase(A.CA, A.wpad + 9*WSLOT, A.outp, A.T + 3*PADW, Wl,
              blockIdx.x, nb, tid);
}

extern "C" void kernel_launch(void* const* d_in, const int* in_sizes, int n_in,
                              void* d_out, int out_size, void* d_ws, size_t ws_size,
                              hipStream_t stream){
  MegaArgs ma;
  ma.x    = (const float*)d_in[0];
  ma.ei   = (const int*)d_in[1];
  ma.w1   = (const float*)d_in[2];  ma.cb0 = (const float*)d_in[3];
  ma.w2   = (const float*)d_in[4];  ma.cb1 = (const float*)d_in[5];
  ma.w3   = (const float*)d_in[6];  ma.cb2 = (const float*)d_in[7];
  ma.g0 = (const float*)d_in[8];  ma.b0 = (const float*)d_in[9];
  ma.m0 = (const float*)d_in[10]; ma.v0 = (const float*)d_in[11];
  ma.g1 = (const float*)d_in[12]; ma.b1 = (const float*)d_in[13];
  ma.m1 = (const float*)d_in[14]; ma.v1 = (const float*)d_in[15];
  ma.g2 = (const float*)d_in[16]; ma.b2 = (const float*)d_in[17];
  ma.m2 = (const float*)d_in[18]; ma.v2 = (const float*)d_in[19];
  ma.wl = (const float*)d_in[20]; ma.linb = (const float*)d_in[21];
  ma.outp = (float*)d_out;

  char* ws = (char*)d_ws;
  size_t off = 0;
  auto alloc = [&](size_t bytes)->char*{
    char* p = ws + off;
    off = (off + bytes + 255) & ~(size_t)255;
    return p;
  };
  ma.cnt   = (int*)alloc((size_t)N_NODES*4);
  ma.slots = (u16*)alloc((size_t)N_NODES*SLOTS*2);    // 6.4 MB
  ma.dis   = (float*)alloc((size_t)(N_NODES+1)*4);    // +1 sentinel (=0)
  ma.S     = (float*)alloc(4*PADW*4);
  ma.T     = (float*)alloc(4*PADW*4);
  ma.wpad  = (u16*)alloc((size_t)10*WSLOT*2);
  const size_t HB = (size_t)N_NODES*PADW*2;           // 19.2MB, stride-192
  const size_t YB = (size_t)(N_NODES+1)*64*2;         // stride-64 (+sentinel row)
  ma.CA = (u16*)alloc(HB);
  ma.CB = (u16*)alloc(HB);
  ma.Y1 = (u16*)alloc(YB);
  ma.Y2 = (u16*)alloc(YB);
  ma.Z  = (u16*)alloc(YB);

  // co-resident grid: __launch_bounds__(256,4) guarantees >=4 blocks/CU by VGPR;
  // LDS 25.6KB allows 6/CU. Confirm via occupancy query (host-side, capture-safe).
  static int gmax = 0;
  if (gmax == 0){
    int bpc = 0;
    if (hipOccupancyMaxActiveBlocksPerMultiprocessor(&bpc, k_mega, 256, 0) != hipSuccess
        || bpc < 1) bpc = 1;
    gmax = bpc * 256;               // 256 CUs on MI355X
    if (gmax > 1024) gmax = 1024;   // 4 blocks/CU target
  }

  void* kargs[] = { (void*)&ma };
  hipLaunchCooperativeKernel((const void*)k_mega, dim3(gmax), dim3(256),
                             kargs, 0, stream);
}

// Round 6
// 397.263 us; speedup vs baseline: 2.5048x; 2.5048x over previous
//
#include <hip/hip_runtime.h>
#include <type_traits>

#define N_NODES 50000
#define N_EDGES 400000
#define DIM     128
#define HID     60
#define NCLS    40
#define F3      180
#define PADW    192
#define LDSW    200
#define SLOTS   64
#define MTILES  3125   // 50000/16
#define WSLOT   (64*192)
#define DISB    196    // ceil(50001/256)
#define WPADB   480    // 10*WSLOT/256
#define PROP_REP 3     // diagnostic: idempotent repetition to surface props in top-5

typedef __bf16 bf16x8 __attribute__((ext_vector_type(8)));
typedef unsigned short u16x8 __attribute__((ext_vector_type(8)));
typedef float  f32x4  __attribute__((ext_vector_type(4)));
typedef unsigned short u16;
typedef unsigned int   u32;

__device__ __forceinline__ u16 f2bf(float f){
  u32 x = __float_as_uint(f);
  x += 0x7fffu + ((x>>16)&1u);   // RNE
  return (u16)(x>>16);
}
__device__ __forceinline__ float blo(u32 v){ return __uint_as_float(v<<16); }
__device__ __forceinline__ float bhi(u32 v){ return __uint_as_float(v & 0xffff0000u); }
__device__ __forceinline__ u32 pk(float a, float b){ return (u32)f2bf(a) | ((u32)f2bf(b)<<16); }

// 8 bf16 cols (one uint4) accumulate with weight wt
__device__ __forceinline__ void acc8(float* a, uint4 V, float wt){
  a[0] = fmaf(wt, blo(V.x), a[0]); a[1] = fmaf(wt, bhi(V.x), a[1]);
  a[2] = fmaf(wt, blo(V.y), a[2]); a[3] = fmaf(wt, bhi(V.y), a[3]);
  a[4] = fmaf(wt, blo(V.z), a[4]); a[5] = fmaf(wt, bhi(V.z), a[5]);
  a[6] = fmaf(wt, blo(V.w), a[6]); a[7] = fmaf(wt, bhi(V.w), a[7]);
}

// ---------- preprocessing: slot-CSR (u16 indices) in ONE scatter pass ----------
__global__ void k_scatter(const int* __restrict__ ei, int* __restrict__ cnt,
                          u16* __restrict__ slots){
  int e = blockIdx.x*blockDim.x + threadIdx.x;
  if (e >= N_EDGES) return;
  int c = ei[N_EDGES + e];
  int pos = atomicAdd(&cnt[c], 1);
  if (pos < SLOTS) slots[c*SLOTS + pos] = (u16)ei[e];
}

// ---------- fused setup: dis/self/pad/n4 | S,T prep | weight pad ----------
struct SetupArgs {
  const float *g0,*b0,*m0,*v0,*cb0;
  const float *g1,*b1,*m1,*v1,*cb1;
  const float *g2,*b2,*m2,*v2,*cb2;
  const float *linb;
  const float *w1,*w2,*w3,*wl;
};
__global__ void k_setup(SetupArgs P, int* __restrict__ cnt, float* __restrict__ dis,
                        u16* __restrict__ slots, u16* __restrict__ wpad,
                        float* __restrict__ S, float* __restrict__ T){
  int b = blockIdx.x;
  if (b < DISB){
    int gid = b*256 + threadIdx.x;
    if (gid > N_NODES) return;
    if (gid == N_NODES){ dis[N_NODES] = 0.f; return; }
    int d = min(cnt[gid], SLOTS - 5);
    dis[gid] = rsqrtf((float)(d + 1));
    int d4 = (d + 4) & ~3;                 // self + pad to multiple of 4
    u16* s = slots + gid*SLOTS;
    s[d] = (u16)gid;                       // self loop (weight = dis[gid])
    for (int p = d + 1; p < d4; ++p) s[p] = (u16)N_NODES;   // zero-weight pads
    cnt[gid] = d4;                         // overwrite with padded count
  } else if (b < DISB + 4){
    int lb = b - DISB, c = threadIdx.x;
    if (c >= PADW) return;
    float s = 0.f, t = 0.f;
    if (lb < 3){
      const float* g  = lb==0?P.g0 :lb==1?P.g1 :P.g2;
      const float* bb = lb==0?P.b0 :lb==1?P.b1 :P.b2;
      const float* m  = lb==0?P.m0 :lb==1?P.m1 :P.m2;
      const float* v  = lb==0?P.v0 :lb==1?P.v1 :P.v2;
      const float* cb = lb==0?P.cb0:lb==1?P.cb1:P.cb2;
      if (c < F3){
        float sv = g[c] * rsqrtf(v[c] + 1e-5f);
        s = sv;
        t = cb[c]*sv + bb[c] - m[c]*sv;    // conv bias folded into BN
      }
    } else if (c < NCLS){ s = 1.f; t = P.linb[c]; }
    S[lb*PADW + c] = s; T[lb*PADW + c] = t;
  } else {
    int g = (b - DISB - 4)*256 + threadIdx.x;
    int sl = g / WSLOT, idx = g % WSLOT;
    int r = idx / 192, k = idx % 192;
    const float* src; int rows, K;
    if (sl < 3)      { src = P.w1 + sl*HID*DIM;      rows = HID;  K = DIM; }
    else if (sl < 6) { src = P.w2 + (sl-3)*HID*F3;   rows = HID;  K = F3;  }
    else if (sl < 9) { src = P.w3 + (sl-6)*HID*F3;   rows = HID;  K = F3;  }
    else             { src = P.wl;                   rows = NCLS; K = F3;  }
    u16 v = 0;
    if (r < rows && k < K) v = f2bf(src[r*K + k]);
    wpad[g] = v;
  }
}

// ---------- dual-stream gather hop: 8 nodes/wave, 8 lanes/node, uint4/lane ----------
// DIAGNOSTIC: body repeated PROP_REP times (idempotent rewrites of identical values)
__global__ __launch_bounds__(256) void k_prop2(
        const u16* __restrict__ inA, u16* __restrict__ outA,
        const float* __restrict__ SA, const float* __restrict__ TA,
        const u16* __restrict__ inB, u16* __restrict__ outB,
        const float* __restrict__ dis, const int* __restrict__ n4a,
        const u16* __restrict__ slots){
  int t = blockIdx.x*256 + threadIdx.x;
  int lane = t & 63, g = lane >> 3, c = lane & 7;
  int node = (t >> 6)*8 + g;
  if (node >= N_NODES) return;
  float di = dis[node];
  int n4 = n4a[node];
  const u16* nb = slots + node*SLOTS;
  #pragma unroll 1
  for (int rep = 0; rep < PROP_REP; ++rep){
    float aA[8] = {0,0,0,0,0,0,0,0}, aB[8] = {0,0,0,0,0,0,0,0};
    for (int e = 0; e < n4; e += 4){
      uint2 s4 = *(const uint2*)(nb + e);
      int r0 = s4.x & 0xffff, r1 = s4.x >> 16;
      int r2 = s4.y & 0xffff, r3 = s4.y >> 16;
      float w0 = dis[r0], w1 = dis[r1], w2 = dis[r2], w3 = dis[r3];
      uint4 A0 = ((const uint4*)(inA + (size_t)r0*64))[c];
      uint4 A1 = ((const uint4*)(inA + (size_t)r1*64))[c];
      uint4 A2 = ((const uint4*)(inA + (size_t)r2*64))[c];
      uint4 A3 = ((const uint4*)(inA + (size_t)r3*64))[c];
      uint4 B0 = ((const uint4*)(inB + (size_t)r0*64))[c];
      uint4 B1 = ((const uint4*)(inB + (size_t)r1*64))[c];
      uint4 B2 = ((const uint4*)(inB + (size_t)r2*64))[c];
      uint4 B3 = ((const uint4*)(inB + (size_t)r3*64))[c];
      acc8(aA, A0, w0); acc8(aA, A1, w1); acc8(aA, A2, w2); acc8(aA, A3, w3);
      acc8(aB, B0, w0); acc8(aB, B1, w1); acc8(aB, B2, w2); acc8(aB, B3, w3);
    }
    int cc = c*8;
    float y0 = di*aA[0]*SA[cc]   + TA[cc],   y1 = di*aA[1]*SA[cc+1] + TA[cc+1];
    float y2 = di*aA[2]*SA[cc+2] + TA[cc+2], y3 = di*aA[3]*SA[cc+3] + TA[cc+3];
    float y4 = di*aA[4]*SA[cc+4] + TA[cc+4], y5 = di*aA[5]*SA[cc+5] + TA[cc+5];
    float y6 = di*aA[6]*SA[cc+6] + TA[cc+6], y7 = di*aA[7]*SA[cc+7] + TA[cc+7];
    u16* oa = outA + (size_t)node*PADW + cc;      // 8B-aligned (offset 60 ok)
    uint2 w01 = {pk(y0,y1), pk(y2,y3)}, w23 = {pk(y4,y5), pk(y6,y7)};
    *(uint2*)(oa)     = w01;
    *(uint2*)(oa + 4) = w23;
    uint4 ob = {pk(di*aB[0],di*aB[1]), pk(di*aB[2],di*aB[3]),
                pk(di*aB[4],di*aB[5]), pk(di*aB[6],di*aB[7])};
    ((uint4*)(outB + (size_t)node*64))[c] = ob;
  }
}

// single-stream hop with S/T epilogue, output stride PADW
__global__ __launch_bounds__(256) void k_prop1(
        const u16* __restrict__ inA, u16* __restrict__ outA,
        const float* __restrict__ SA, const float* __restrict__ TA,
        const float* __restrict__ dis, const int* __restrict__ n4a,
        const u16* __restrict__ slots){
  int t = blockIdx.x*256 + threadIdx.x;
  int lane = t & 63, g = lane >> 3, c = lane & 7;
  int node = (t >> 6)*8 + g;
  if (node >= N_NODES) return;
  float di = dis[node];
  int n4 = n4a[node];
  const u16* nb = slots + node*SLOTS;
  #pragma unroll 1
  for (int rep = 0; rep < PROP_REP; ++rep){
    float a[8] = {0,0,0,0,0,0,0,0};
    for (int e = 0; e < n4; e += 4){
      uint2 s4 = *(const uint2*)(nb + e);
      int r0 = s4.x & 0xffff, r1 = s4.x >> 16;
      int r2 = s4.y & 0xffff, r3 = s4.y >> 16;
      float w0 = dis[r0], w1 = dis[r1], w2 = dis[r2], w3 = dis[r3];
      uint4 v0 = ((const uint4*)(inA + (size_t)r0*64))[c];
      uint4 v1 = ((const uint4*)(inA + (size_t)r1*64))[c];
      uint4 v2 = ((const uint4*)(inA + (size_t)r2*64))[c];
      uint4 v3 = ((const uint4*)(inA + (size_t)r3*64))[c];
      acc8(a, v0, w0); acc8(a, v1, w1); acc8(a, v2, w2); acc8(a, v3, w3);
    }
    int cc = c*8;
    float y0 = di*a[0]*SA[cc]   + TA[cc],   y1 = di*a[1]*SA[cc+1] + TA[cc+1];
    float y2 = di*a[2]*SA[cc+2] + TA[cc+2], y3 = di*a[3]*SA[cc+3] + TA[cc+3];
    float y4 = di*a[4]*SA[cc+4] + TA[cc+4], y5 = di*a[5]*SA[cc+5] + TA[cc+5];
    float y6 = di*a[6]*SA[cc+6] + TA[cc+6], y7 = di*a[7]*SA[cc+7] + TA[cc+7];
    u16* oa = outA + (size_t)node*PADW + cc;
    uint2 w01 = {pk(y0,y1), pk(y2,y3)}, w23 = {pk(y4,y5), pk(y6,y7)};
    *(uint2*)(oa)     = w01;
    *(uint2*)(oa + 4) = w23;
  }
}

// ---------- A-fragment loaders ----------
__device__ __forceinline__ bf16x8 lda8(const u16* p){ return *(const bf16x8*)p; }
__device__ __forceinline__ bf16x8 lda8(const float* p){
  f32x4 v0 = ((const f32x4*)p)[0];
  f32x4 v1 = ((const f32x4*)p)[1];
  u16x8 t;
  #pragma unroll
  for (int j = 0; j < 4; ++j){ t[j] = f2bf(v0[j]); t[j+4] = f2bf(v1[j]); }
  return __builtin_bit_cast(bf16x8, t);
}

// ---------- fused 3-power GEMM: A read ONCE into registers, W re-staged per p ----------
template<typename TA, int KS>
__global__ __launch_bounds__(256) void k_gemm3(const TA* __restrict__ A, int lda,
        const u16* __restrict__ Wbase, u16* __restrict__ C0,
        u16* __restrict__ Y1, u16* __restrict__ Y2,
        const float* __restrict__ S, const float* __restrict__ T){
  __shared__ u16 Wl[64*LDSW];
  int tid = threadIdx.x;
  int mt = blockIdx.x*4 + (tid >> 6);
  bool active = mt < MTILES;
  int lane = tid & 63, rr = lane & 15, kg = lane >> 4;
  int mrow = active ? mt*16 + rr : 0;
  const TA* Ap = A + (size_t)mrow*lda + kg*8;
  bf16x8 a[KS];
  #pragma unroll
  for (int ks = 0; ks < KS; ++ks) a[ks] = lda8(Ap + ks*32);
  #pragma unroll
  for (int p = 0; p < 3; ++p){
    const u16* Wp = Wbase + p*WSLOT;
    for (int t2 = tid; t2 < 1536; t2 += 256){
      int r = t2 / 24, c8 = t2 % 24;
      *(u16x8*)(&Wl[r*LDSW + c8*8]) = *(const u16x8*)(Wp + r*192 + c8*8);
    }
    __syncthreads();
    f32x4 acc[4] = {{0,0,0,0},{0,0,0,0},{0,0,0,0},{0,0,0,0}};
    #pragma unroll
    for (int ks = 0; ks < KS; ++ks){
      int kb = ks*32 + kg*8;
      #pragma unroll
      for (int ct = 0; ct < 4; ++ct){
        bf16x8 b = *(const bf16x8*)(&Wl[(ct*16 + rr)*LDSW + kb]);
        acc[ct] = __builtin_amdgcn_mfma_f32_16x16x32_bf16(a[ks], b, acc[ct], 0, 0, 0);
      }
    }
    if (active){
      int orow = mt*16 + kg*4;
      u16* out = (p==0) ? C0 : (p==1) ? Y1 : Y2;
      int  ldo = (p==0) ? PADW : 64;
      #pragma unroll
      for (int ct = 0; ct < 4; ++ct){
        int col = ct*16 + rr;
        if (col < HID){
          float sS = (p==0) ? S[col] : 1.f;
          float tT = (p==0) ? T[col] : 0.f;
          #pragma unroll
          for (int r2 = 0; r2 < 4; ++r2)
            out[(size_t)(orow + r2)*ldo + col] = f2bf(acc[ct][r2]*sS + tT);
        }
      }
    }
    __syncthreads();
  }
}

// ---------- final linear: CA[50000,192]@Wl^T -> f32 out [50000,40] ----------
__global__ __launch_bounds__(256) void k_gemmf(const u16* __restrict__ A,
        const u16* __restrict__ Wp, float* __restrict__ out,
        const float* __restrict__ S, const float* __restrict__ T){
  __shared__ u16 Wl[64*LDSW];
  int tid = threadIdx.x;
  for (int t2 = tid; t2 < 1536; t2 += 256){
    int r = t2 / 24, c8 = t2 % 24;
    *(u16x8*)(&Wl[r*LDSW + c8*8]) = *(const u16x8*)(Wp + r*192 + c8*8);
  }
  __syncthreads();
  int mt = blockIdx.x*4 + (tid >> 6);
  if (mt >= MTILES) return;
  int lane = tid & 63, rr = lane & 15, kg = lane >> 4;
  const u16* Ap = A + (size_t)(mt*16 + rr)*PADW + kg*8;
  f32x4 acc[4] = {{0,0,0,0},{0,0,0,0},{0,0,0,0},{0,0,0,0}};
  for (int ks = 0; ks < 6; ++ks){
    bf16x8 a = *(const bf16x8*)(Ap + ks*32);
    int kb = ks*32 + kg*8;
    #pragma unroll
    for (int ct = 0; ct < 4; ++ct){
      bf16x8 b = *(const bf16x8*)(&Wl[(ct*16 + rr)*LDSW + kb]);
      acc[ct] = __builtin_amdgcn_mfma_f32_16x16x32_bf16(a, b, acc[ct], 0, 0, 0);
    }
  }
  int orow = mt*16 + kg*4;
  #pragma unroll
  for (int ct = 0; ct < 4; ++ct){
    int col = ct*16 + rr;
    if (col < NCLS){
      float tT = T[col];
      #pragma unroll
      for (int r2 = 0; r2 < 4; ++r2)
        out[(size_t)(orow + r2)*NCLS + col] = acc[ct][r2] + tT;
    }
  }
}

extern "C" void kernel_launch(void* const* d_in, const int* in_sizes, int n_in,
                              void* d_out, int out_size, void* d_ws, size_t ws_size,
                              hipStream_t stream){
  const float* x    = (const float*)d_in[0];
  const int*   ei   = (const int*)d_in[1];
  const float* w1   = (const float*)d_in[2];
  const float* cb1  = (const float*)d_in[3];
  const float* w2   = (const float*)d_in[4];
  const float* cb2  = (const float*)d_in[5];
  const float* w3   = (const float*)d_in[6];
  const float* cb3  = (const float*)d_in[7];
  const float* bn1g = (const float*)d_in[8],  *bn1b = (const float*)d_in[9];
  const float* bn1m = (const float*)d_in[10], *bn1v = (const float*)d_in[11];
  const float* bn2g = (const float*)d_in[12], *bn2b = (const float*)d_in[13];
  const float* bn2m = (const float*)d_in[14], *bn2v = (const float*)d_in[15];
  const float* bn3g = (const float*)d_in[16], *bn3b = (const float*)d_in[17];
  const float* bn3m = (const float*)d_in[18], *bn3v = (const float*)d_in[19];
  const float* linW = (const float*)d_in[20];
  const float* linb = (const float*)d_in[21];
  float* outp = (float*)d_out;

  char* ws = (char*)d_ws;
  size_t off = 0;
  auto alloc = [&](size_t bytes)->char*{
    char* p = ws + off;
    off = (off + bytes + 255) & ~(size_t)255;
    return p;
  };
  int*   cnt   = (int*)alloc((size_t)N_NODES*4);
  u16*   slots = (u16*)alloc((size_t)N_NODES*SLOTS*2);   // 6.4 MB
  float* dis   = (float*)alloc((size_t)(N_NODES+1)*4);   // +1 sentinel (=0)
  float* S     = (float*)alloc(4*PADW*4);
  float* T     = (float*)alloc(4*PADW*4);
  u16*   wpad  = (u16*)alloc((size_t)10*WSLOT*2);
  const size_t HB = (size_t)N_NODES*PADW*2;       // 19.2MB, stride-192
  const size_t YB = (size_t)(N_NODES+1)*64*2;     // stride-64 (+sentinel row)
  u16* CA = (u16*)alloc(HB);
  u16* CB = (u16*)alloc(HB);
  u16* Y1 = (u16*)alloc(YB);
  u16* Y2 = (u16*)alloc(YB);
  u16* Z  = (u16*)alloc(YB);

  hipMemsetAsync(cnt, 0, (size_t)N_NODES*4, stream);
  k_scatter<<<(N_EDGES+255)/256, 256, 0, stream>>>(ei, cnt, slots);
  SetupArgs sa{bn1g,bn1b,bn1m,bn1v,cb1, bn2g,bn2b,bn2m,bn2v,cb2,
               bn3g,bn3b,bn3m,bn3v,cb3, linb, w1,w2,w3,linW};
  k_setup<<<DISB + 4 + WPADB, 256, 0, stream>>>(sa, cnt, dis, slots, wpad, S, T);

  const int GB = (MTILES + 3)/4;          // 782 blocks, 4 m-tiles each
  const int PB = (N_NODES + 31)/32;       // 1563 blocks, 32 nodes each

  // layer 1: A = x (f32, K=128); Y_p = A@W_p^T, then hops (GEMM-first commute)
  k_gemm3<float,4><<<GB, 256, 0, stream>>>(x, DIM, wpad + 0*WSLOT, CA, Y1, Y2,
                                           S + 0*PADW, T + 0*PADW);
  k_prop2<<<PB, 256, 0, stream>>>(Y1, CA + 60, S + 0*PADW + 60, T + 0*PADW + 60,
                                  Y2, Z, dis, cnt, slots);
  k_prop1<<<PB, 256, 0, stream>>>(Z, CA + 120, S + 0*PADW + 120, T + 0*PADW + 120,
                                  dis, cnt, slots);
  // layer 2: A = CA (bf16, K=192)
  k_gemm3<u16,6><<<GB, 256, 0, stream>>>(CA, PADW, wpad + 3*WSLOT, CB, Y1, Y2,
                                         S + 1*PADW, T + 1*PADW);
  k_prop2<<<PB, 256, 0, stream>>>(Y1, CB + 60, S + 1*PADW + 60, T + 1*PADW + 60,
                                  Y2, Z, dis, cnt, slots);
  k_prop1<<<PB, 256, 0, stream>>>(Z, CB + 120, S + 1*PADW + 120, T + 1*PADW + 120,
                                  dis, cnt, slots);
  // layer 3: A = CB -> CA
  k_gemm3<u16,6><<<GB, 256, 0, stream>>>(CB, PADW, wpad + 6*WSLOT, CA, Y1, Y2,
                                         S + 2*PADW, T + 2*PADW);
  k_prop2<<<PB, 256, 0, stream>>>(Y1, CA + 60, S + 2*PADW + 60, T + 2*PADW + 60,
                                  Y2, Z, dis, cnt, slots);
  k_prop1<<<PB, 256, 0, stream>>>(Z, CA + 120, S + 2*PADW + 120, T + 2*PADW + 120,
                                  dis, cnt, slots);

  // final linear -> f32 out
  k_gemmf<<<GB, 256, 0, stream>>>(CA, wpad + 9*WSLOT, outp, S + 3*PADW, T + 3*PADW);
}

// Round 7
// 333.419 us; speedup vs baseline: 2.9844x; 1.1915x over previous
//
#include <hip/hip_runtime.h>
#include <type_traits>

#define N_NODES 50000
#define N_EDGES 400000
#define DIM     128
#define HID     60
#define NCLS    40
#define F3      180
#define PADW    192
#define LDSW    200
#define SLOTS   64
#define MTILES  3125   // 50000/16
#define WSLOT   (64*192)
#define DISB    196    // ceil(50001/256)
#define WPADB   480    // 10*WSLOT/256
#define GEMM_REP 3     // diagnostic: idempotent repetition to surface GEMMs in top-5

typedef __bf16 bf16x8 __attribute__((ext_vector_type(8)));
typedef unsigned short u16x8 __attribute__((ext_vector_type(8)));
typedef float  f32x4  __attribute__((ext_vector_type(4)));
typedef unsigned short u16;
typedef unsigned int   u32;

__device__ __forceinline__ u16 f2bf(float f){
  u32 x = __float_as_uint(f);
  x += 0x7fffu + ((x>>16)&1u);   // RNE
  return (u16)(x>>16);
}
__device__ __forceinline__ float blo(u32 v){ return __uint_as_float(v<<16); }
__device__ __forceinline__ float bhi(u32 v){ return __uint_as_float(v & 0xffff0000u); }
__device__ __forceinline__ u32 pk(float a, float b){ return (u32)f2bf(a) | ((u32)f2bf(b)<<16); }

// 8 bf16 cols (one uint4) accumulate with weight wt
__device__ __forceinline__ void acc8(float* a, uint4 V, float wt){
  a[0] = fmaf(wt, blo(V.x), a[0]); a[1] = fmaf(wt, bhi(V.x), a[1]);
  a[2] = fmaf(wt, blo(V.y), a[2]); a[3] = fmaf(wt, bhi(V.y), a[3]);
  a[4] = fmaf(wt, blo(V.z), a[4]); a[5] = fmaf(wt, bhi(V.z), a[5]);
  a[6] = fmaf(wt, blo(V.w), a[6]); a[7] = fmaf(wt, bhi(V.w), a[7]);
}

// ---------- preprocessing: slot-CSR (u16 indices) in ONE scatter pass ----------
__global__ void k_scatter(const int* __restrict__ ei, int* __restrict__ cnt,
                          u16* __restrict__ slots){
  int e = blockIdx.x*blockDim.x + threadIdx.x;
  if (e >= N_EDGES) return;
  int c = ei[N_EDGES + e];
  int pos = atomicAdd(&cnt[c], 1);
  if (pos < SLOTS) slots[c*SLOTS + pos] = (u16)ei[e];
}

// ---------- fused setup: dis/self/pad/n4 | S,T prep | weight pad ----------
struct SetupArgs {
  const float *g0,*b0,*m0,*v0,*cb0;
  const float *g1,*b1,*m1,*v1,*cb1;
  const float *g2,*b2,*m2,*v2,*cb2;
  const float *linb;
  const float *w1,*w2,*w3,*wl;
};
__global__ void k_setup(SetupArgs P, int* __restrict__ cnt, float* __restrict__ dis,
                        u16* __restrict__ slots, u16* __restrict__ wpad,
                        float* __restrict__ S, float* __restrict__ T){
  int b = blockIdx.x;
  if (b < DISB){
    int gid = b*256 + threadIdx.x;
    if (gid > N_NODES) return;
    if (gid == N_NODES){ dis[N_NODES] = 0.f; return; }
    int d = min(cnt[gid], SLOTS - 5);
    dis[gid] = rsqrtf((float)(d + 1));
    int d4 = (d + 4) & ~3;                 // self + pad to multiple of 4
    u16* s = slots + gid*SLOTS;
    s[d] = (u16)gid;                       // self loop (weight = dis[gid])
    for (int p = d + 1; p < d4; ++p) s[p] = (u16)N_NODES;   // zero-weight pads
    cnt[gid] = d4;                         // overwrite with padded count
  } else if (b < DISB + 4){
    int lb = b - DISB, c = threadIdx.x;
    if (c >= PADW) return;
    float s = 0.f, t = 0.f;
    if (lb < 3){
      const float* g  = lb==0?P.g0 :lb==1?P.g1 :P.g2;
      const float* bb = lb==0?P.b0 :lb==1?P.b1 :P.b2;
      const float* m  = lb==0?P.m0 :lb==1?P.m1 :P.m2;
      const float* v  = lb==0?P.v0 :lb==1?P.v1 :P.v2;
      const float* cb = lb==0?P.cb0:lb==1?P.cb1:P.cb2;
      if (c < F3){
        float sv = g[c] * rsqrtf(v[c] + 1e-5f);
        s = sv;
        t = cb[c]*sv + bb[c] - m[c]*sv;    // conv bias folded into BN
      }
    } else if (c < NCLS){ s = 1.f; t = P.linb[c]; }
    S[lb*PADW + c] = s; T[lb*PADW + c] = t;
  } else {
    int g = (b - DISB - 4)*256 + threadIdx.x;
    int sl = g / WSLOT, idx = g % WSLOT;
    int r = idx / 192, k = idx % 192;
    const float* src; int rows, K;
    if (sl < 3)      { src = P.w1 + sl*HID*DIM;      rows = HID;  K = DIM; }
    else if (sl < 6) { src = P.w2 + (sl-3)*HID*F3;   rows = HID;  K = F3;  }
    else if (sl < 9) { src = P.w3 + (sl-6)*HID*F3;   rows = HID;  K = F3;  }
    else             { src = P.wl;                   rows = NCLS; K = F3;  }
    u16 v = 0;
    if (r < rows && k < K) v = f2bf(src[r*K + k]);
    wpad[g] = v;
  }
}

// ---------- dual-stream gather hop: 8 nodes/wave, 8 lanes/node, uint4/lane ----------
__global__ __launch_bounds__(256) void k_prop2(
        const u16* __restrict__ inA, u16* __restrict__ outA,
        const float* __restrict__ SA, const float* __restrict__ TA,
        const u16* __restrict__ inB, u16* __restrict__ outB,
        const float* __restrict__ dis, const int* __restrict__ n4a,
        const u16* __restrict__ slots){
  int t = blockIdx.x*256 + threadIdx.x;
  int lane = t & 63, g = lane >> 3, c = lane & 7;
  int node = (t >> 6)*8 + g;
  if (node >= N_NODES) return;
  float di = dis[node];
  int n4 = n4a[node];
  const u16* nb = slots + node*SLOTS;
  float aA[8] = {0,0,0,0,0,0,0,0}, aB[8] = {0,0,0,0,0,0,0,0};
  for (int e = 0; e < n4; e += 4){
    uint2 s4 = *(const uint2*)(nb + e);
    int r0 = s4.x & 0xffff, r1 = s4.x >> 16;
    int r2 = s4.y & 0xffff, r3 = s4.y >> 16;
    float w0 = dis[r0], w1 = dis[r1], w2 = dis[r2], w3 = dis[r3];
    uint4 A0 = ((const uint4*)(inA + (size_t)r0*64))[c];
    uint4 A1 = ((const uint4*)(inA + (size_t)r1*64))[c];
    uint4 A2 = ((const uint4*)(inA + (size_t)r2*64))[c];
    uint4 A3 = ((const uint4*)(inA + (size_t)r3*64))[c];
    uint4 B0 = ((const uint4*)(inB + (size_t)r0*64))[c];
    uint4 B1 = ((const uint4*)(inB + (size_t)r1*64))[c];
    uint4 B2 = ((const uint4*)(inB + (size_t)r2*64))[c];
    uint4 B3 = ((const uint4*)(inB + (size_t)r3*64))[c];
    acc8(aA, A0, w0); acc8(aA, A1, w1); acc8(aA, A2, w2); acc8(aA, A3, w3);
    acc8(aB, B0, w0); acc8(aB, B1, w1); acc8(aB, B2, w2); acc8(aB, B3, w3);
  }
  int cc = c*8;
  float y0 = di*aA[0]*SA[cc]   + TA[cc],   y1 = di*aA[1]*SA[cc+1] + TA[cc+1];
  float y2 = di*aA[2]*SA[cc+2] + TA[cc+2], y3 = di*aA[3]*SA[cc+3] + TA[cc+3];
  float y4 = di*aA[4]*SA[cc+4] + TA[cc+4], y5 = di*aA[5]*SA[cc+5] + TA[cc+5];
  float y6 = di*aA[6]*SA[cc+6] + TA[cc+6], y7 = di*aA[7]*SA[cc+7] + TA[cc+7];
  u16* oa = outA + (size_t)node*PADW + cc;      // 8B-aligned (offset 60 ok)
  uint2 w01 = {pk(y0,y1), pk(y2,y3)}, w23 = {pk(y4,y5), pk(y6,y7)};
  *(uint2*)(oa)     = w01;
  *(uint2*)(oa + 4) = w23;
  uint4 ob = {pk(di*aB[0],di*aB[1]), pk(di*aB[2],di*aB[3]),
              pk(di*aB[4],di*aB[5]), pk(di*aB[6],di*aB[7])};
  ((uint4*)(outB + (size_t)node*64))[c] = ob;
}

// single-stream hop with S/T epilogue, output stride PADW
__global__ __launch_bounds__(256) void k_prop1(
        const u16* __restrict__ inA, u16* __restrict__ outA,
        const float* __restrict__ SA, const float* __restrict__ TA,
        const float* __restrict__ dis, const int* __restrict__ n4a,
        const u16* __restrict__ slots){
  int t = blockIdx.x*256 + threadIdx.x;
  int lane = t & 63, g = lane >> 3, c = lane & 7;
  int node = (t >> 6)*8 + g;
  if (node >= N_NODES) return;
  float di = dis[node];
  int n4 = n4a[node];
  const u16* nb = slots + node*SLOTS;
  float a[8] = {0,0,0,0,0,0,0,0};
  for (int e = 0; e < n4; e += 4){
    uint2 s4 = *(const uint2*)(nb + e);
    int r0 = s4.x & 0xffff, r1 = s4.x >> 16;
    int r2 = s4.y & 0xffff, r3 = s4.y >> 16;
    float w0 = dis[r0], w1 = dis[r1], w2 = dis[r2], w3 = dis[r3];
    uint4 v0 = ((const uint4*)(inA + (size_t)r0*64))[c];
    uint4 v1 = ((const uint4*)(inA + (size_t)r1*64))[c];
    uint4 v2 = ((const uint4*)(inA + (size_t)r2*64))[c];
    uint4 v3 = ((const uint4*)(inA + (size_t)r3*64))[c];
    acc8(a, v0, w0); acc8(a, v1, w1); acc8(a, v2, w2); acc8(a, v3, w3);
  }
  int cc = c*8;
  float y0 = di*a[0]*SA[cc]   + TA[cc],   y1 = di*a[1]*SA[cc+1] + TA[cc+1];
  float y2 = di*a[2]*SA[cc+2] + TA[cc+2], y3 = di*a[3]*SA[cc+3] + TA[cc+3];
  float y4 = di*a[4]*SA[cc+4] + TA[cc+4], y5 = di*a[5]*SA[cc+5] + TA[cc+5];
  float y6 = di*a[6]*SA[cc+6] + TA[cc+6], y7 = di*a[7]*SA[cc+7] + TA[cc+7];
  u16* oa = outA + (size_t)node*PADW + cc;
  uint2 w01 = {pk(y0,y1), pk(y2,y3)}, w23 = {pk(y4,y5), pk(y6,y7)};
  *(uint2*)(oa)     = w01;
  *(uint2*)(oa + 4) = w23;
}

// ---------- A-fragment loaders ----------
__device__ __forceinline__ bf16x8 lda8(const u16* p){ return *(const bf16x8*)p; }
__device__ __forceinline__ bf16x8 lda8(const float* p){
  f32x4 v0 = ((const f32x4*)p)[0];
  f32x4 v1 = ((const f32x4*)p)[1];
  u16x8 t;
  #pragma unroll
  for (int j = 0; j < 4; ++j){ t[j] = f2bf(v0[j]); t[j+4] = f2bf(v1[j]); }
  return __builtin_bit_cast(bf16x8, t);
}

// ---------- fused 3-power GEMM: A read ONCE into registers, W re-staged per p ----------
// DIAGNOSTIC: per-power body repeated GEMM_REP times (idempotent rewrites)
template<typename TA, int KS>
__global__ __launch_bounds__(256) void k_gemm3(const TA* __restrict__ A, int lda,
        const u16* __restrict__ Wbase, u16* __restrict__ C0,
        u16* __restrict__ Y1, u16* __restrict__ Y2,
        const float* __restrict__ S, const float* __restrict__ T){
  __shared__ u16 Wl[64*LDSW];
  int tid = threadIdx.x;
  int mt = blockIdx.x*4 + (tid >> 6);
  bool active = mt < MTILES;
  int lane = tid & 63, rr = lane & 15, kg = lane >> 4;
  int mrow = active ? mt*16 + rr : 0;
  const TA* Ap = A + (size_t)mrow*lda + kg*8;
  bf16x8 a[KS];
  #pragma unroll
  for (int ks = 0; ks < KS; ++ks) a[ks] = lda8(Ap + ks*32);
  #pragma unroll
  for (int p = 0; p < 3; ++p){
    const u16* Wp = Wbase + p*WSLOT;
    #pragma unroll 1
    for (int rep = 0; rep < GEMM_REP; ++rep){
      for (int t2 = tid; t2 < 1536; t2 += 256){
        int r = t2 / 24, c8 = t2 % 24;
        *(u16x8*)(&Wl[r*LDSW + c8*8]) = *(const u16x8*)(Wp + r*192 + c8*8);
      }
      __syncthreads();
      f32x4 acc[4] = {{0,0,0,0},{0,0,0,0},{0,0,0,0},{0,0,0,0}};
      #pragma unroll
      for (int ks = 0; ks < KS; ++ks){
        int kb = ks*32 + kg*8;
        #pragma unroll
        for (int ct = 0; ct < 4; ++ct){
          bf16x8 b = *(const bf16x8*)(&Wl[(ct*16 + rr)*LDSW + kb]);
          acc[ct] = __builtin_amdgcn_mfma_f32_16x16x32_bf16(a[ks], b, acc[ct], 0, 0, 0);
        }
      }
      if (active){
        int orow = mt*16 + kg*4;
        u16* out = (p==0) ? C0 : (p==1) ? Y1 : Y2;
        int  ldo = (p==0) ? PADW : 64;
        #pragma unroll
        for (int ct = 0; ct < 4; ++ct){
          int col = ct*16 + rr;
          if (col < HID){
            float sS = (p==0) ? S[col] : 1.f;
            float tT = (p==0) ? T[col] : 0.f;
            #pragma unroll
            for (int r2 = 0; r2 < 4; ++r2)
              out[(size_t)(orow + r2)*ldo + col] = f2bf(acc[ct][r2]*sS + tT);
          }
        }
      }
      __syncthreads();
    }
  }
}

// ---------- final linear: CA[50000,192]@Wl^T -> f32 out [50000,40] ----------
// DIAGNOSTIC: compute body repeated GEMM_REP times (idempotent rewrites)
__global__ __launch_bounds__(256) void k_gemmf(const u16* __restrict__ A,
        const u16* __restrict__ Wp, float* __restrict__ out,
        const float* __restrict__ S, const float* __restrict__ T){
  __shared__ u16 Wl[64*LDSW];
  int tid = threadIdx.x;
  for (int t2 = tid; t2 < 1536; t2 += 256){
    int r = t2 / 24, c8 = t2 % 24;
    *(u16x8*)(&Wl[r*LDSW + c8*8]) = *(const u16x8*)(Wp + r*192 + c8*8);
  }
  __syncthreads();
  int mt = blockIdx.x*4 + (tid >> 6);
  if (mt >= MTILES) return;
  int lane = tid & 63, rr = lane & 15, kg = lane >> 4;
  const u16* Ap = A + (size_t)(mt*16 + rr)*PADW + kg*8;
  #pragma unroll 1
  for (int rep = 0; rep < GEMM_REP; ++rep){
    f32x4 acc[4] = {{0,0,0,0},{0,0,0,0},{0,0,0,0},{0,0,0,0}};
    for (int ks = 0; ks < 6; ++ks){
      bf16x8 a = *(const bf16x8*)(Ap + ks*32);
      int kb = ks*32 + kg*8;
      #pragma unroll
      for (int ct = 0; ct < 4; ++ct){
        bf16x8 b = *(const bf16x8*)(&Wl[(ct*16 + rr)*LDSW + kb]);
        acc[ct] = __builtin_amdgcn_mfma_f32_16x16x32_bf16(a, b, acc[ct], 0, 0, 0);
      }
    }
    int orow = mt*16 + kg*4;
    #pragma unroll
    for (int ct = 0; ct < 4; ++ct){
      int col = ct*16 + rr;
      if (col < NCLS){
        float tT = T[col];
        #pragma unroll
        for (int r2 = 0; r2 < 4; ++r2)
          out[(size_t)(orow + r2)*NCLS + col] = acc[ct][r2] + tT;
      }
    }
  }
}

extern "C" void kernel_launch(void* const* d_in, const int* in_sizes, int n_in,
                              void* d_out, int out_size, void* d_ws, size_t ws_size,
                              hipStream_t stream){
  const float* x    = (const float*)d_in[0];
  const int*   ei   = (const int*)d_in[1];
  const float* w1   = (const float*)d_in[2];
  const float* cb1  = (const float*)d_in[3];
  const float* w2   = (const float*)d_in[4];
  const float* cb2  = (const float*)d_in[5];
  const float* w3   = (const float*)d_in[6];
  const float* cb3  = (const float*)d_in[7];
  const float* bn1g = (const float*)d_in[8],  *bn1b = (const float*)d_in[9];
  const float* bn1m = (const float*)d_in[10], *bn1v = (const float*)d_in[11];
  const float* bn2g = (const float*)d_in[12], *bn2b = (const float*)d_in[13];
  const float* bn2m = (const float*)d_in[14], *bn2v = (const float*)d_in[15];
  const float* bn3g = (const float*)d_in[16], *bn3b = (const float*)d_in[17];
  const float* bn3m = (const float*)d_in[18], *bn3v = (const float*)d_in[19];
  const float* linW = (const float*)d_in[20];
  const float* linb = (const float*)d_in[21];
  float* outp = (float*)d_out;

  char* ws = (char*)d_ws;
  size_t off = 0;
  auto alloc = [&](size_t bytes)->char*{
    char* p = ws + off;
    off = (off + bytes + 255) & ~(size_t)255;
    return p;
  };
  int*   cnt   = (int*)alloc((size_t)N_NODES*4);
  u16*   slots = (u16*)alloc((size_t)N_NODES*SLOTS*2);   // 6.4 MB
  float* dis   = (float*)alloc((size_t)(N_NODES+1)*4);   // +1 sentinel (=0)
  float* S     = (float*)alloc(4*PADW*4);
  float* T     = (float*)alloc(4*PADW*4);
  u16*   wpad  = (u16*)alloc((size_t)10*WSLOT*2);
  const size_t HB = (size_t)N_NODES*PADW*2;       // 19.2MB, stride-192
  const size_t YB = (size_t)(N_NODES+1)*64*2;     // stride-64 (+sentinel row)
  u16* CA = (u16*)alloc(HB);
  u16* CB = (u16*)alloc(HB);
  u16* Y1 = (u16*)alloc(YB);
  u16* Y2 = (u16*)alloc(YB);
  u16* Z  = (u16*)alloc(YB);

  hipMemsetAsync(cnt, 0, (size_t)N_NODES*4, stream);
  k_scatter<<<(N_EDGES+255)/256, 256, 0, stream>>>(ei, cnt, slots);
  SetupArgs sa{bn1g,bn1b,bn1m,bn1v,cb1, bn2g,bn2b,bn2m,bn2v,cb2,
               bn3g,bn3b,bn3m,bn3v,cb3, linb, w1,w2,w3,linW};
  k_setup<<<DISB + 4 + WPADB, 256, 0, stream>>>(sa, cnt, dis, slots, wpad, S, T);

  const int GB = (MTILES + 3)/4;          // 782 blocks, 4 m-tiles each
  const int PB = (N_NODES + 31)/32;       // 1563 blocks, 32 nodes each

  // layer 1: A = x (f32, K=128); Y_p = A@W_p^T, then hops (GEMM-first commute)
  k_gemm3<float,4><<<GB, 256, 0, stream>>>(x, DIM, wpad + 0*WSLOT, CA, Y1, Y2,
                                           S + 0*PADW, T + 0*PADW);
  k_prop2<<<PB, 256, 0, stream>>>(Y1, CA + 60, S + 0*PADW + 60, T + 0*PADW + 60,
                                  Y2, Z, dis, cnt, slots);
  k_prop1<<<PB, 256, 0, stream>>>(Z, CA + 120, S + 0*PADW + 120, T + 0*PADW + 120,
                                  dis, cnt, slots);
  // layer 2: A = CA (bf16, K=192)
  k_gemm3<u16,6><<<GB, 256, 0, stream>>>(CA, PADW, wpad + 3*WSLOT, CB, Y1, Y2,
                                         S + 1*PADW, T + 1*PADW);
  k_prop2<<<PB, 256, 0, stream>>>(Y1, CB + 60, S + 1*PADW + 60, T + 1*PADW + 60,
                                  Y2, Z, dis, cnt, slots);
  k_prop1<<<PB, 256, 0, stream>>>(Z, CB + 120, S + 1*PADW + 120, T + 1*PADW + 120,
                                  dis, cnt, slots);
  // layer 3: A = CB -> CA
  k_gemm3<u16,6><<<GB, 256, 0, stream>>>(CB, PADW, wpad + 6*WSLOT, CA, Y1, Y2,
                                         S + 2*PADW, T + 2*PADW);
  k_prop2<<<PB, 256, 0, stream>>>(Y1, CA + 60, S + 2*PADW + 60, T + 2*PADW + 60,
                                  Y2, Z, dis, cnt, slots);
  k_prop1<<<PB, 256, 0, stream>>>(Z, CA + 120, S + 2*PADW + 120, T + 2*PADW + 120,
                                  dis, cnt, slots);

  // final linear -> f32 out
  k_gemmf<<<GB, 256, 0, stream>>>(CA, wpad + 9*WSLOT, outp, S + 3*PADW, T + 3*PADW);
}

// Round 8
// 289.359 us; speedup vs baseline: 3.4388x; 1.1523x over previous
//
#include <hip/hip_runtime.h>
#include <type_traits>

#define N_NODES 50000
#define N_EDGES 400000
#define DIM     128
#define HID     60
#define NCLS    40
#define F3      180
#define PADW    192
#define LDSW    200
#define SLOTS   64
#define MTILES  3125   // 50000/16
#define WSLOT   (64*192)
#define DISB    196    // ceil(50001/256)
#define WPADB   480    // 10*WSLOT/256

typedef __bf16 bf16x8 __attribute__((ext_vector_type(8)));
typedef unsigned short u16x8 __attribute__((ext_vector_type(8)));
typedef float  f32x4  __attribute__((ext_vector_type(4)));
typedef unsigned short u16;
typedef unsigned int   u32;

__device__ __forceinline__ u16 f2bf(float f){
  u32 x = __float_as_uint(f);
  x += 0x7fffu + ((x>>16)&1u);   // RNE
  return (u16)(x>>16);
}
__device__ __forceinline__ float blo(u32 v){ return __uint_as_float(v<<16); }
__device__ __forceinline__ float bhi(u32 v){ return __uint_as_float(v & 0xffff0000u); }
__device__ __forceinline__ u32 pk(float a, float b){ return (u32)f2bf(a) | ((u32)f2bf(b)<<16); }

// 8 bf16 cols (one uint4) accumulate with weight wt
__device__ __forceinline__ void acc8(float* a, uint4 V, float wt){
  a[0] = fmaf(wt, blo(V.x), a[0]); a[1] = fmaf(wt, bhi(V.x), a[1]);
  a[2] = fmaf(wt, blo(V.y), a[2]); a[3] = fmaf(wt, bhi(V.y), a[3]);
  a[4] = fmaf(wt, blo(V.z), a[4]); a[5] = fmaf(wt, bhi(V.z), a[5]);
  a[6] = fmaf(wt, blo(V.w), a[6]); a[7] = fmaf(wt, bhi(V.w), a[7]);
}

// ---------- preprocessing: slot-CSR (u16 indices) in ONE scatter pass ----------
__global__ void k_scatter(const int* __restrict__ ei, int* __restrict__ cnt,
                          u16* __restrict__ slots){
  int e = blockIdx.x*blockDim.x + threadIdx.x;
  if (e >= N_EDGES) return;
  int c = ei[N_EDGES + e];
  int pos = atomicAdd(&cnt[c], 1);
  if (pos < SLOTS) slots[c*SLOTS + pos] = (u16)ei[e];
}

// ---------- fused setup: dis/self/pad/n4 | S,T prep | weight pad ----------
struct SetupArgs {
  const float *g0,*b0,*m0,*v0,*cb0;
  const float *g1,*b1,*m1,*v1,*cb1;
  const float *g2,*b2,*m2,*v2,*cb2;
  const float *linb;
  const float *w1,*w2,*w3,*wl;
};
__global__ void k_setup(SetupArgs P, int* __restrict__ cnt, float* __restrict__ dis,
                        u16* __restrict__ slots, u16* __restrict__ wpad,
                        float* __restrict__ S, float* __restrict__ T){
  int b = blockIdx.x;
  if (b < DISB){
    int gid = b*256 + threadIdx.x;
    if (gid > N_NODES) return;
    if (gid == N_NODES){ dis[N_NODES] = 0.f; return; }
    int d = min(cnt[gid], SLOTS - 5);
    dis[gid] = rsqrtf((float)(d + 1));
    int d4 = (d + 4) & ~3;                 // self + pad to multiple of 4
    u16* s = slots + gid*SLOTS;
    s[d] = (u16)gid;                       // self loop (weight = dis[gid])
    for (int p = d + 1; p < d4; ++p) s[p] = (u16)N_NODES;   // zero-weight pads
    cnt[gid] = d4;                         // overwrite with padded count
  } else if (b < DISB + 4){
    int lb = b - DISB, c = threadIdx.x;
    if (c >= PADW) return;
    float s = 0.f, t = 0.f;
    if (lb < 3){
      const float* g  = lb==0?P.g0 :lb==1?P.g1 :P.g2;
      const float* bb = lb==0?P.b0 :lb==1?P.b1 :P.b2;
      const float* m  = lb==0?P.m0 :lb==1?P.m1 :P.m2;
      const float* v  = lb==0?P.v0 :lb==1?P.v1 :P.v2;
      const float* cb = lb==0?P.cb0:lb==1?P.cb1:P.cb2;
      if (c < F3){
        float sv = g[c] * rsqrtf(v[c] + 1e-5f);
        s = sv;
        t = cb[c]*sv + bb[c] - m[c]*sv;    // conv bias folded into BN
      }
    } else if (c < NCLS){ s = 1.f; t = P.linb[c]; }
    S[lb*PADW + c] = s; T[lb*PADW + c] = t;
  } else {
    int g = (b - DISB - 4)*256 + threadIdx.x;
    int sl = g / WSLOT, idx = g % WSLOT;
    int r = idx / 192, k = idx % 192;
    const float* src; int rows, K;
    if (sl < 3)      { src = P.w1 + sl*HID*DIM;      rows = HID;  K = DIM; }
    else if (sl < 6) { src = P.w2 + (sl-3)*HID*F3;   rows = HID;  K = F3;  }
    else if (sl < 9) { src = P.w3 + (sl-6)*HID*F3;   rows = HID;  K = F3;  }
    else             { src = P.wl;                   rows = NCLS; K = F3;  }
    u16 v = 0;
    if (r < rows && k < K) v = f2bf(src[r*K + k]);
    wpad[g] = v;
  }
}

// ---------- dual-stream gather hop: 8 nodes/wave, 8 lanes/node, uint4/lane ----------
__global__ __launch_bounds__(256) void k_prop2(
        const u16* __restrict__ inA, u16* __restrict__ outA,
        const float* __restrict__ SA, const float* __restrict__ TA,
        const u16* __restrict__ inB, u16* __restrict__ outB,
        const float* __restrict__ dis, const int* __restrict__ n4a,
        const u16* __restrict__ slots){
  int t = blockIdx.x*256 + threadIdx.x;
  int lane = t & 63, g = lane >> 3, c = lane & 7;
  int node = (t >> 6)*8 + g;
  if (node >= N_NODES) return;
  float di = dis[node];
  int n4 = n4a[node];
  const u16* nb = slots + node*SLOTS;
  float aA[8] = {0,0,0,0,0,0,0,0}, aB[8] = {0,0,0,0,0,0,0,0};
  for (int e = 0; e < n4; e += 4){
    uint2 s4 = *(const uint2*)(nb + e);
    int r0 = s4.x & 0xffff, r1 = s4.x >> 16;
    int r2 = s4.y & 0xffff, r3 = s4.y >> 16;
    float w0 = dis[r0], w1 = dis[r1], w2 = dis[r2], w3 = dis[r3];
    uint4 A0 = ((const uint4*)(inA + (size_t)r0*64))[c];
    uint4 A1 = ((const uint4*)(inA + (size_t)r1*64))[c];
    uint4 A2 = ((const uint4*)(inA + (size_t)r2*64))[c];
    uint4 A3 = ((const uint4*)(inA + (size_t)r3*64))[c];
    uint4 B0 = ((const uint4*)(inB + (size_t)r0*64))[c];
    uint4 B1 = ((const uint4*)(inB + (size_t)r1*64))[c];
    uint4 B2 = ((const uint4*)(inB + (size_t)r2*64))[c];
    uint4 B3 = ((const uint4*)(inB + (size_t)r3*64))[c];
    acc8(aA, A0, w0); acc8(aA, A1, w1); acc8(aA, A2, w2); acc8(aA, A3, w3);
    acc8(aB, B0, w0); acc8(aB, B1, w1); acc8(aB, B2, w2); acc8(aB, B3, w3);
  }
  int cc = c*8;
  float y0 = di*aA[0]*SA[cc]   + TA[cc],   y1 = di*aA[1]*SA[cc+1] + TA[cc+1];
  float y2 = di*aA[2]*SA[cc+2] + TA[cc+2], y3 = di*aA[3]*SA[cc+3] + TA[cc+3];
  float y4 = di*aA[4]*SA[cc+4] + TA[cc+4], y5 = di*aA[5]*SA[cc+5] + TA[cc+5];
  float y6 = di*aA[6]*SA[cc+6] + TA[cc+6], y7 = di*aA[7]*SA[cc+7] + TA[cc+7];
  u16* oa = outA + (size_t)node*PADW + cc;      // 8B-aligned (offset 60 ok)
  uint2 w01 = {pk(y0,y1), pk(y2,y3)}, w23 = {pk(y4,y5), pk(y6,y7)};
  *(uint2*)(oa)     = w01;
  *(uint2*)(oa + 4) = w23;
  uint4 ob = {pk(di*aB[0],di*aB[1]), pk(di*aB[2],di*aB[3]),
              pk(di*aB[4],di*aB[5]), pk(di*aB[6],di*aB[7])};
  ((uint4*)(outB + (size_t)node*64))[c] = ob;
}

// single-stream hop with S/T epilogue, output stride PADW
__global__ __launch_bounds__(256) void k_prop1(
        const u16* __restrict__ inA, u16* __restrict__ outA,
        const float* __restrict__ SA, const float* __restrict__ TA,
        const float* __restrict__ dis, const int* __restrict__ n4a,
        const u16* __restrict__ slots){
  int t = blockIdx.x*256 + threadIdx.x;
  int lane = t & 63, g = lane >> 3, c = lane & 7;
  int node = (t >> 6)*8 + g;
  if (node >= N_NODES) return;
  float di = dis[node];
  int n4 = n4a[node];
  const u16* nb = slots + node*SLOTS;
  float a[8] = {0,0,0,0,0,0,0,0};
  for (int e = 0; e < n4; e += 4){
    uint2 s4 = *(const uint2*)(nb + e);
    int r0 = s4.x & 0xffff, r1 = s4.x >> 16;
    int r2 = s4.y & 0xffff, r3 = s4.y >> 16;
    float w0 = dis[r0], w1 = dis[r1], w2 = dis[r2], w3 = dis[r3];
    uint4 v0 = ((const uint4*)(inA + (size_t)r0*64))[c];
    uint4 v1 = ((const uint4*)(inA + (size_t)r1*64))[c];
    uint4 v2 = ((const uint4*)(inA + (size_t)r2*64))[c];
    uint4 v3 = ((const uint4*)(inA + (size_t)r3*64))[c];
    acc8(a, v0, w0); acc8(a, v1, w1); acc8(a, v2, w2); acc8(a, v3, w3);
  }
  int cc = c*8;
  float y0 = di*a[0]*SA[cc]   + TA[cc],   y1 = di*a[1]*SA[cc+1] + TA[cc+1];
  float y2 = di*a[2]*SA[cc+2] + TA[cc+2], y3 = di*a[3]*SA[cc+3] + TA[cc+3];
  float y4 = di*a[4]*SA[cc+4] + TA[cc+4], y5 = di*a[5]*SA[cc+5] + TA[cc+5];
  float y6 = di*a[6]*SA[cc+6] + TA[cc+6], y7 = di*a[7]*SA[cc+7] + TA[cc+7];
  u16* oa = outA + (size_t)node*PADW + cc;
  uint2 w01 = {pk(y0,y1), pk(y2,y3)}, w23 = {pk(y4,y5), pk(y6,y7)};
  *(uint2*)(oa)     = w01;
  *(uint2*)(oa + 4) = w23;
}

// ---------- A-fragment loaders ----------
__device__ __forceinline__ bf16x8 lda8(const u16* p){ return *(const bf16x8*)p; }
__device__ __forceinline__ bf16x8 lda8(const float* p){
  f32x4 v0 = ((const f32x4*)p)[0];
  f32x4 v1 = ((const f32x4*)p)[1];
  u16x8 t;
  #pragma unroll
  for (int j = 0; j < 4; ++j){ t[j] = f2bf(v0[j]); t[j+4] = f2bf(v1[j]); }
  return __builtin_bit_cast(bf16x8, t);
}

// ---------- fused 3-power GEMM: A read ONCE into registers, W re-staged per p ----------
// Epilogue vectorized: per-wave 16x64 tile repacked through LDS -> uint4 stores
// (wave-private Ol tile => no extra __syncthreads; same values as scalar path)
template<typename TA, int KS>
__global__ __launch_bounds__(256) void k_gemm3(const TA* __restrict__ A, int lda,
        const u16* __restrict__ Wbase, u16* __restrict__ C0,
        u16* __restrict__ Y1, u16* __restrict__ Y2,
        const float* __restrict__ S, const float* __restrict__ T){
  __shared__ u16 Wl[64*LDSW];
  __shared__ u16 Ol[4][16][64];            // per-wave output repack tile (8KB)
  int tid = threadIdx.x;
  int mt = blockIdx.x*4 + (tid >> 6);
  bool active = mt < MTILES;
  int lane = tid & 63, rr = lane & 15, kg = lane >> 4;
  int mrow = active ? mt*16 + rr : 0;
  const TA* Ap = A + (size_t)mrow*lda + kg*8;
  bf16x8 a[KS];
  #pragma unroll
  for (int ks = 0; ks < KS; ++ks) a[ks] = lda8(Ap + ks*32);
  #pragma unroll
  for (int p = 0; p < 3; ++p){
    const u16* Wp = Wbase + p*WSLOT;
    for (int t2 = tid; t2 < 1536; t2 += 256){
      int r = t2 / 24, c8 = t2 % 24;
      *(u16x8*)(&Wl[r*LDSW + c8*8]) = *(const u16x8*)(Wp + r*192 + c8*8);
    }
    __syncthreads();
    f32x4 acc[4] = {{0,0,0,0},{0,0,0,0},{0,0,0,0},{0,0,0,0}};
    #pragma unroll
    for (int ks = 0; ks < KS; ++ks){
      int kb = ks*32 + kg*8;
      #pragma unroll
      for (int ct = 0; ct < 4; ++ct){
        bf16x8 b = *(const bf16x8*)(&Wl[(ct*16 + rr)*LDSW + kb]);
        acc[ct] = __builtin_amdgcn_mfma_f32_16x16x32_bf16(a[ks], b, acc[ct], 0, 0, 0);
      }
    }
    if (active){
      int q = tid >> 6;
      u16* ol = &Ol[q][0][0];
      // write this wave's 16x64 tile into LDS (cols 60-63: acc=0 via W zero-pad)
      #pragma unroll
      for (int ct = 0; ct < 4; ++ct){
        int col = ct*16 + rr;
        float sS = (p==0) ? S[col] : 1.f;
        float tT = (p==0) ? T[col] : 0.f;
        #pragma unroll
        for (int r2 = 0; r2 < 4; ++r2)
          ol[(kg*4 + r2)*64 + col] = f2bf(acc[ct][r2]*sS + tT);
      }
      // read back coalesced: 4 lanes/row, 2 uint4 (32B) per lane
      int row = lane >> 2, ch = (lane & 3)*2;
      uint4 v0 = *(const uint4*)&ol[row*64 + ch*8];
      uint4 v1 = *(const uint4*)&ol[row*64 + ch*8 + 8];
      u16* out = (p==0) ? C0 : (p==1) ? Y1 : Y2;
      int  ldo = (p==0) ? PADW : 64;
      u16* op = out + (size_t)(mt*16 + row)*ldo + ch*8;
      *(uint4*)op       = v0;
      *(uint4*)(op + 8) = v1;
    }
    __syncthreads();
  }
}

// ---------- final linear: CA[50000,192]@Wl^T -> f32 out [50000,40] ----------
__global__ __launch_bounds__(256) void k_gemmf(const u16* __restrict__ A,
        const u16* __restrict__ Wp, float* __restrict__ out,
        const float* __restrict__ S, const float* __restrict__ T){
  __shared__ u16 Wl[64*LDSW];
  int tid = threadIdx.x;
  for (int t2 = tid; t2 < 1536; t2 += 256){
    int r = t2 / 24, c8 = t2 % 24;
    *(u16x8*)(&Wl[r*LDSW + c8*8]) = *(const u16x8*)(Wp + r*192 + c8*8);
  }
  __syncthreads();
  int mt = blockIdx.x*4 + (tid >> 6);
  if (mt >= MTILES) return;
  int lane = tid & 63, rr = lane & 15, kg = lane >> 4;
  const u16* Ap = A + (size_t)(mt*16 + rr)*PADW + kg*8;
  f32x4 acc[4] = {{0,0,0,0},{0,0,0,0},{0,0,0,0},{0,0,0,0}};
  for (int ks = 0; ks < 6; ++ks){
    bf16x8 a = *(const bf16x8*)(Ap + ks*32);
    int kb = ks*32 + kg*8;
    #pragma unroll
    for (int ct = 0; ct < 4; ++ct){
      bf16x8 b = *(const bf16x8*)(&Wl[(ct*16 + rr)*LDSW + kb]);
      acc[ct] = __builtin_amdgcn_mfma_f32_16x16x32_bf16(a, b, acc[ct], 0, 0, 0);
    }
  }
  int orow = mt*16 + kg*4;
  #pragma unroll
  for (int ct = 0; ct < 4; ++ct){
    int col = ct*16 + rr;
    if (col < NCLS){
      float tT = T[col];
      #pragma unroll
      for (int r2 = 0; r2 < 4; ++r2)
        out[(size_t)(orow + r2)*NCLS + col] = acc[ct][r2] + tT;
    }
  }
}

extern "C" void kernel_launch(void* const* d_in, const int* in_sizes, int n_in,
                              void* d_out, int out_size, void* d_ws, size_t ws_size,
                              hipStream_t stream){
  const float* x    = (const float*)d_in[0];
  const int*   ei   = (const int*)d_in[1];
  const float* w1   = (const float*)d_in[2];
  const float* cb1  = (const float*)d_in[3];
  const float* w2   = (const float*)d_in[4];
  const float* cb2  = (const float*)d_in[5];
  const float* w3   = (const float*)d_in[6];
  const float* cb3  = (const float*)d_in[7];
  const float* bn1g = (const float*)d_in[8],  *bn1b = (const float*)d_in[9];
  const float* bn1m = (const float*)d_in[10], *bn1v = (const float*)d_in[11];
  const float* bn2g = (const float*)d_in[12], *bn2b = (const float*)d_in[13];
  const float* bn2m = (const float*)d_in[14], *bn2v = (const float*)d_in[15];
  const float* bn3g = (const float*)d_in[16], *bn3b = (const float*)d_in[17];
  const float* bn3m = (const float*)d_in[18], *bn3v = (const float*)d_in[19];
  const float* linW = (const float*)d_in[20];
  const float* linb = (const float*)d_in[21];
  float* outp = (float*)d_out;

  char* ws = (char*)d_ws;
  size_t off = 0;
  auto alloc = [&](size_t bytes)->char*{
    char* p = ws + off;
    off = (off + bytes + 255) & ~(size_t)255;
    return p;
  };
  int*   cnt   = (int*)alloc((size_t)N_NODES*4);
  u16*   slots = (u16*)alloc((size_t)N_NODES*SLOTS*2);   // 6.4 MB
  float* dis   = (float*)alloc((size_t)(N_NODES+1)*4);   // +1 sentinel (=0)
  float* S     = (float*)alloc(4*PADW*4);
  float* T     = (float*)alloc(4*PADW*4);
  u16*   wpad  = (u16*)alloc((size_t)10*WSLOT*2);
  const size_t HB = (size_t)N_NODES*PADW*2;       // 19.2MB, stride-192
  const size_t YB = (size_t)(N_NODES+1)*64*2;     // stride-64 (+sentinel row)
  u16* CA = (u16*)alloc(HB);
  u16* CB = (u16*)alloc(HB);
  u16* Y1 = (u16*)alloc(YB);
  u16* Y2 = (u16*)alloc(YB);
  u16* Z  = (u16*)alloc(YB);

  hipMemsetAsync(cnt, 0, (size_t)N_NODES*4, stream);
  k_scatter<<<(N_EDGES+255)/256, 256, 0, stream>>>(ei, cnt, slots);
  SetupArgs sa{bn1g,bn1b,bn1m,bn1v,cb1, bn2g,bn2b,bn2m,bn2v,cb2,
               bn3g,bn3b,bn3m,bn3v,cb3, linb, w1,w2,w3,linW};
  k_setup<<<DISB + 4 + WPADB, 256, 0, stream>>>(sa, cnt, dis, slots, wpad, S, T);

  const int GB = (MTILES + 3)/4;          // 782 blocks, 4 m-tiles each
  const int PB = (N_NODES + 31)/32;       // 1563 blocks, 32 nodes each

  // layer 1: A = x (f32, K=128); Y_p = A@W_p^T, then hops (GEMM-first commute)
  k_gemm3<float,4><<<GB, 256, 0, stream>>>(x, DIM, wpad + 0*WSLOT, CA, Y1, Y2,
                                           S + 0*PADW, T + 0*PADW);
  k_prop2<<<PB, 256, 0, stream>>>(Y1, CA + 60, S + 0*PADW + 60, T + 0*PADW + 60,
                                  Y2, Z, dis, cnt, slots);
  k_prop1<<<PB, 256, 0, stream>>>(Z, CA + 120, S + 0*PADW + 120, T + 0*PADW + 120,
                                  dis, cnt, slots);
  // layer 2: A = CA (bf16, K=192)
  k_gemm3<u16,6><<<GB, 256, 0, stream>>>(CA, PADW, wpad + 3*WSLOT, CB, Y1, Y2,
                                         S + 1*PADW, T + 1*PADW);
  k_prop2<<<PB, 256, 0, stream>>>(Y1, CB + 60, S + 1*PADW + 60, T + 1*PADW + 60,
                                  Y2, Z, dis, cnt, slots);
  k_prop1<<<PB, 256, 0, stream>>>(Z, CB + 120, S + 1*PADW + 120, T + 1*PADW + 120,
                                  dis, cnt, slots);
  // layer 3: A = CB -> CA
  k_gemm3<u16,6><<<GB, 256, 0, stream>>>(CB, PADW, wpad + 6*WSLOT, CA, Y1, Y2,
                                         S + 2*PADW, T + 2*PADW);
  k_prop2<<<PB, 256, 0, stream>>>(Y1, CA + 60, S + 2*PADW + 60, T + 2*PADW + 60,
                                  Y2, Z, dis, cnt, slots);
  k_prop1<<<PB, 256, 0, stream>>>(Z, CA + 120, S + 2*PADW + 120, T + 2*PADW + 120,
                                  dis, cnt, slots);

  // final linear -> f32 out
  k_gemmf<<<GB, 256, 0, stream>>>(CA, wpad + 9*WSLOT, outp, S + 3*PADW, T + 3*PADW);
}